// Round 4
// baseline (2370.507 us; speedup 1.0000x reference)
//
#include <hip/hip_runtime.h>
#include <cstdint>
#include <cstddef>
#include <cmath>

#define DD 128

typedef short bf16x8 __attribute__((ext_vector_type(8)));
typedef float f32x4 __attribute__((ext_vector_type(4)));

static __device__ __forceinline__ short f2bf(float f){
  union { float f; uint32_t u; } v; v.f = f;
  uint32_t r = v.u + 0x7FFFu + ((v.u >> 16) & 1u);   // RNE
  return (short)(r >> 16);
}
static __device__ __forceinline__ float bf2f(short h){
  union { uint32_t u; float f; } v; v.u = ((uint32_t)(uint16_t)h) << 16;
  return v.f;
}

// ============================================================================
// f32 GEMM mimicking BLAS sgemm rounding: per output element a SINGLE
// sequential fmaf chain over k=0..127 (matches OpenBLAS/XLA microkernels).
// Block 256: tx=tid&31 -> cols tx*4..+4 ; ty=tid>>5 -> rows ty*4..+4; 32-row tiles.
// EP 0: Y = acc + bias
// EP 1: Y = ((acc + bias) + T2[src]) + T3[dst]; fused f64 BN stats of stored vals
// EP 2: Y = acc + relu(((Y - m)*r)*gamma + beta)     (e_new; Y holds pre_e)
// EP 3: A-stage = sigmoid(X); den[dst]+=acc, num[dst]+=acc*Vh[src] (f32 atomics)
// ============================================================================
template<int EP>
__global__ __launch_bounds__(256, 1) void gemm32_k(
    const float* __restrict__ X, const float* __restrict__ W,
    const float* __restrict__ bias, float* __restrict__ Y,
    int M, int rowTiles,
    const int* __restrict__ src, const int* __restrict__ dst,
    const float* __restrict__ T2, const float* __restrict__ T3,
    const float* __restrict__ mF, const float* __restrict__ rF,
    const float* __restrict__ gammaF, const float* __restrict__ betaF,
    float* __restrict__ den, float* __restrict__ num,
    const float* __restrict__ Vh,
    double* __restrict__ eSum, double* __restrict__ eSumSq)
{
  __shared__ float sW[128 * 128];
  __shared__ float sA[128 * 32];
  __shared__ double redS[(EP == 1) ? 1024 : 1];
  __shared__ double redQ[(EP == 1) ? 1024 : 1];

  const int tid = threadIdx.x, tx = tid & 31, ty = tid >> 5, c0 = tx * 4;

  for (int t = tid; t < 128 * 128 / 4; t += 256)
    ((f32x4*)sW)[t] = ((const f32x4*)W)[t];

  float bias_c[4];
  #pragma unroll
  for (int j = 0; j < 4; ++j) bias_c[j] = bias ? bias[c0 + j] : 0.0f;

  double st_s[4] = {0,0,0,0}, st_q[4] = {0,0,0,0};
  __syncthreads();

  for (int rt = blockIdx.x; rt < rowTiles; rt += gridDim.x){
    const int rowBase = rt * 32;
    { // stage A (32 rows x 128 k), transposed to [k][row]
      int rr = tid & 31;
      int kk = (tid >> 5) * 16;
      int ar = rowBase + rr; if (ar >= M) ar = M - 1;
      const float* xp = X + (size_t)ar * DD + kk;
      #pragma unroll
      for (int q = 0; q < 4; ++q){
        f32x4 v = *(const f32x4*)(xp + q * 4);
        #pragma unroll
        for (int j = 0; j < 4; ++j){
          float f = v[j];
          if (EP == 3) f = 1.0f / (1.0f + expf(-f));   // sigmoid in f32
          sA[(kk + q*4 + j) * 32 + rr] = f;
        }
      }
    }
    __syncthreads();

    float acc[4][4] = {};
    for (int k = 0; k < 128; ++k){            // sequential k: BLAS-order chain
      f32x4 a = *(const f32x4*)&sA[k * 32 + ty * 4];
      f32x4 b = *(const f32x4*)&sW[k * 128 + c0];
      #pragma unroll
      for (int i = 0; i < 4; ++i)
        #pragma unroll
        for (int j = 0; j < 4; ++j)
          acc[i][j] = fmaf(a[i], b[j], acc[i][j]);
    }

    #pragma unroll
    for (int i = 0; i < 4; ++i){
      int r = rowBase + ty * 4 + i;
      if (r < M){
        size_t base = (size_t)r * DD + c0;
        if (EP == 0){
          #pragma unroll
          for (int j = 0; j < 4; ++j) Y[base + j] = acc[i][j] + bias_c[j];
        } else if (EP == 1){
          int s = src[r], d = dst[r];
          f32x4 t2 = *(const f32x4*)&T2[(size_t)s * DD + c0];
          f32x4 t3 = *(const f32x4*)&T3[(size_t)d * DD + c0];
          #pragma unroll
          for (int j = 0; j < 4; ++j){
            float o = ((acc[i][j] + bias_c[j]) + t2[j]) + t3[j];  // ref add order
            Y[base + j] = o;
            st_s[j] += (double)o;
            st_q[j] += (double)o * (double)o;
          }
        } else if (EP == 2){
          f32x4 pe = *(const f32x4*)&Y[base];      // pre_e (stored f32)
          #pragma unroll
          for (int j = 0; j < 4; ++j){
            float xm = pe[j] - mF[c0 + j];
            float t1 = xm * rF[c0 + j];
            float t2v = t1 * gammaF[c0 + j];
            float t3v = t2v + betaF[c0 + j];
            float t = fmaxf(t3v, 0.0f);
            Y[base + j] = acc[i][j] + t;           // e_new = e_emb + relu(bn)
          }
        } else { // EP 3
          int s = src[r], d = dst[r];
          f32x4 vh = *(const f32x4*)&Vh[(size_t)s * DD + c0];
          #pragma unroll
          for (int j = 0; j < 4; ++j){
            atomicAdd(&den[(size_t)d * DD + c0 + j], acc[i][j]);
            atomicAdd(&num[(size_t)d * DD + c0 + j], acc[i][j] * vh[j]);
          }
        }
      }
    }
    __syncthreads();
  }

  if (EP == 1){
    const int idx = tx * 8 + ty;
    #pragma unroll
    for (int j = 0; j < 4; ++j){ redS[idx*4+j] = st_s[j]; redQ[idx*4+j] = st_q[j]; }
    __syncthreads();
    if (ty == 0){
      #pragma unroll
      for (int j = 0; j < 4; ++j){
        double s = 0.0, q = 0.0;
        #pragma unroll
        for (int t = 0; t < 8; ++t){ s += redS[(tx*8+t)*4+j]; q += redQ[(tx*8+t)*4+j]; }
        atomicAdd(&eSum[c0+j], s);
        atomicAdd(&eSumSq[c0+j], q);
      }
    }
  }
}

// e-BN params: f64 stats -> f32 mean and f32 rsqrt (np op order: 1/sqrt(v+eps))
__global__ void finalizeE_k(const double* __restrict__ sum, const double* __restrict__ sumsq,
                            double M, float* __restrict__ mF, float* __restrict__ rF)
{
  int c = threadIdx.x;
  double m = sum[c] / M;
  double v = sumsq[c] / M - m * m;
  float vf = (float)v;
  mF[c] = (float)m;
  rF[c] = 1.0f / sqrtf(vf + 1e-5f);
}

// pre_h = Uh + num/(den + 1e-5f), all f32, in place over Uh
__global__ void combine_k(float* __restrict__ UhPreH, const float* __restrict__ num,
                          const float* __restrict__ den, long total4)
{
  for (long i = (long)blockIdx.x * blockDim.x + threadIdx.x; i < total4;
       i += (long)gridDim.x * blockDim.x){
    f32x4 u = ((const f32x4*)UhPreH)[i];
    f32x4 n = ((const f32x4*)num)[i];
    f32x4 d = ((const f32x4*)den)[i];
    f32x4 o;
    #pragma unroll
    for (int j = 0; j < 4; ++j) o[j] = u[j] + n[j] / (d[j] + 1e-5f);
    ((f32x4*)UhPreH)[i] = o;
  }
}

// column stats (f32 in, f64 accum)
__global__ void stats64_k(const float* __restrict__ X, int M,
                          double* __restrict__ sum, double* __restrict__ sumsq)
{
  const int col = threadIdx.x & 127;
  const int half = threadIdx.x >> 7;
  double s = 0.0, q = 0.0;
  for (int r = blockIdx.x * 2 + half; r < M; r += gridDim.x * 2){
    double v = (double)X[(size_t)r * DD + col];
    s += v; q += v * v;
  }
  __shared__ double sS[256], sQ[256];
  sS[threadIdx.x] = s; sQ[threadIdx.x] = q;
  __syncthreads();
  if (half == 0){
    atomicAdd(&sum[col],   sS[col] + sS[col + 128]);
    atomicAdd(&sumsq[col], sQ[col] + sQ[col + 128]);
  }
}

__global__ void finalize64_k(const double* __restrict__ sum, const double* __restrict__ sumsq,
                             double M, const float* __restrict__ gamma, const float* __restrict__ beta,
                             double* __restrict__ scale, double* __restrict__ shift)
{
  int c = threadIdx.x;
  double m = sum[c] / M;
  double var = sumsq[c] / M - m * m;
  double sc = (double)gamma[c] / sqrt(var + 1e-5);
  scale[c] = sc;
  shift[c] = (double)beta[c] - m * sc;
}

// ---------------- split-bf16 MFMA GEMM: h_new = h@Wemb_n + relu(bn(pre_h)) ----
// (post-division path: not error-amplified, near-f32 accuracy is plenty)
__global__ __launch_bounds__(256, 2) void hfinal_mfma_k(
    const float* __restrict__ X, const float* __restrict__ W,
    float* __restrict__ Y, int M, int rowTiles,
    const float* __restrict__ preH,
    const double* __restrict__ hSc, const double* __restrict__ hSh)
{
  const int tid = threadIdx.x;
  const int lane = tid & 63;
  const int wv = tid >> 6;
  const int l15 = lane & 15;
  const int lg = lane >> 4;
  const int colBase = blockIdx.y * 64;

  __shared__ short sW[2][64][136];
  for (int t = tid; t < 64 * 128; t += 256){
    int k = t >> 6, nl = t & 63;
    float w = W[k * DD + colBase + nl];
    short hi = f2bf(w);
    sW[0][nl][k] = hi;
    sW[1][nl][k] = f2bf(w - bf2f(hi));
  }
  __syncthreads();

  bf16x8 Bhi[4][4], Blo[4][4];
  #pragma unroll
  for (int ct = 0; ct < 4; ++ct)
    #pragma unroll
    for (int ks = 0; ks < 4; ++ks){
      Bhi[ct][ks] = *(const bf16x8*)&sW[0][ct*16 + l15][ks*32 + lg*8];
      Blo[ct][ks] = *(const bf16x8*)&sW[1][ct*16 + l15][ks*32 + lg*8];
    }

  for (int rt = blockIdx.x; rt < rowTiles; rt += gridDim.x){
    int arow = rt * 64 + wv * 16 + l15;
    if (arow >= M) arow = M - 1;
    const f32x4* xr = (const f32x4*)(X + (size_t)arow * DD);

    bf16x8 Ahi[4], Alo[4];
    #pragma unroll
    for (int ks = 0; ks < 4; ++ks){
      f32x4 a0 = xr[ks*8 + lg*2];
      f32x4 a1 = xr[ks*8 + lg*2 + 1];
      float av[8];
      #pragma unroll
      for (int j = 0; j < 4; ++j){ av[j] = a0[j]; av[4+j] = a1[j]; }
      #pragma unroll
      for (int j = 0; j < 8; ++j){
        short hi = f2bf(av[j]);
        Ahi[ks][j] = hi;
        Alo[ks][j] = f2bf(av[j] - bf2f(hi));
      }
    }

    f32x4 acc[4];
    #pragma unroll
    for (int ct = 0; ct < 4; ++ct) acc[ct] = (f32x4){0.f, 0.f, 0.f, 0.f};
    #pragma unroll
    for (int ct = 0; ct < 4; ++ct)
      #pragma unroll
      for (int ks = 0; ks < 4; ++ks){
        acc[ct] = __builtin_amdgcn_mfma_f32_16x16x32_bf16(Ahi[ks], Bhi[ct][ks], acc[ct], 0, 0, 0);
        acc[ct] = __builtin_amdgcn_mfma_f32_16x16x32_bf16(Ahi[ks], Blo[ct][ks], acc[ct], 0, 0, 0);
        acc[ct] = __builtin_amdgcn_mfma_f32_16x16x32_bf16(Alo[ks], Bhi[ct][ks], acc[ct], 0, 0, 0);
      }

    const int r0 = rt * 64 + wv * 16 + lg * 4;
    #pragma unroll
    for (int reg = 0; reg < 4; ++reg){
      int r = r0 + reg;
      if (r < M){
        #pragma unroll
        for (int ct = 0; ct < 4; ++ct){
          int c = colBase + ct*16 + l15;
          double t = (double)preH[(size_t)r * DD + c] * hSc[c] + hSh[c];
          float tv = t > 0.0 ? (float)t : 0.0f;
          Y[(size_t)r * DD + c] = acc[ct][reg] + tv;
        }
      }
    }
  }
}

extern "C" void kernel_launch(void* const* d_in, const int* in_sizes, int n_in,
                              void* d_out, int out_size, void* d_ws, size_t ws_size,
                              hipStream_t stream)
{
  const float* h  = (const float*)d_in[0];
  const float* e  = (const float*)d_in[1];
  const int* src  = (const int*)d_in[2];
  const int* dst  = (const int*)d_in[3];
  const float* Wemb_n   = (const float*)d_in[4];
  const float* Wemb_e   = (const float*)d_in[5];
  const float* Wemb_eta = (const float*)d_in[6];
  const float* Uw  = (const float*)d_in[7];  const float* Ub  = (const float*)d_in[8];
  const float* Vw  = (const float*)d_in[9];  const float* Vb  = (const float*)d_in[10];
  const float* W1w = (const float*)d_in[11]; const float* W1b = (const float*)d_in[12];
  const float* W2w = (const float*)d_in[13]; const float* W2b = (const float*)d_in[14];
  const float* W3w = (const float*)d_in[15]; const float* W3b = (const float*)d_in[16];
  const float* h_gamma = (const float*)d_in[17]; const float* h_beta = (const float*)d_in[18];
  const float* e_gamma = (const float*)d_in[19]; const float* e_beta = (const float*)d_in[20];

  const int NN = in_sizes[0] / DD;   // 50000
  const int NE = in_sizes[2];        // 400000

  // workspace: W2h | W3h | Vh | den | num (all f32 NN*DD) | f64 stats | f32 mF,rF
  char* wsp = (char*)d_ws;
  float* W2h = (float*)wsp;  wsp += (size_t)NN * DD * sizeof(float);
  float* W3h = (float*)wsp;  wsp += (size_t)NN * DD * sizeof(float);
  float* Vh  = (float*)wsp;  wsp += (size_t)NN * DD * sizeof(float);
  float* den = (float*)wsp;  wsp += (size_t)NN * DD * sizeof(float);
  float* num = (float*)wsp;  wsp += (size_t)NN * DD * sizeof(float);
  double* stats = (double*)wsp; wsp += 6 * DD * sizeof(double);
  double* eSum = stats;        double* eSumSq = stats + DD;
  double* hSum = stats + 2*DD; double* hSumSq = stats + 3*DD;
  double* hScale = stats + 4*DD; double* hShift = stats + 5*DD;
  float* mF = (float*)wsp;   wsp += DD * sizeof(float);
  float* rF = (float*)wsp;   wsp += DD * sizeof(float);

  float* h_new_out = (float*)d_out;                    // Uh -> pre_h -> h_new
  float* e_out     = (float*)d_out + (size_t)NN * DD;  // pre_e -> e_new

  const int rtN32 = (NN + 31) / 32;   // 1563
  const int rtE32 = (NE + 31) / 32;   // 12500
  const int rtN64 = (NN + 63) / 64;
  dim3 blk(256);

  hipMemsetAsync(den, 0, (size_t)2 * NN * DD * sizeof(float), stream);  // den+num
  hipMemsetAsync(stats, 0, (size_t)4 * DD * sizeof(double), stream);    // sums

  // node GEMMs, f32 BLAS-order
  gemm32_k<0><<<rtN32, blk, 0, stream>>>(h, Uw, Ub, h_new_out, NN, rtN32,
      nullptr,nullptr,nullptr,nullptr,nullptr,nullptr,nullptr,nullptr,nullptr,nullptr,nullptr,nullptr,nullptr);
  gemm32_k<0><<<rtN32, blk, 0, stream>>>(h, Vw, Vb, Vh, NN, rtN32,
      nullptr,nullptr,nullptr,nullptr,nullptr,nullptr,nullptr,nullptr,nullptr,nullptr,nullptr,nullptr,nullptr);
  gemm32_k<0><<<rtN32, blk, 0, stream>>>(h, W2w, W2b, W2h, NN, rtN32,
      nullptr,nullptr,nullptr,nullptr,nullptr,nullptr,nullptr,nullptr,nullptr,nullptr,nullptr,nullptr,nullptr);
  gemm32_k<0><<<rtN32, blk, 0, stream>>>(h, W3w, W3b, W3h, NN, rtN32,
      nullptr,nullptr,nullptr,nullptr,nullptr,nullptr,nullptr,nullptr,nullptr,nullptr,nullptr,nullptr,nullptr);

  // pre_e = ((e@W1 + W1b) + W2h[src]) + W3h[dst] -> e_out; fused f64 stats
  gemm32_k<1><<<4096, blk, 0, stream>>>(e, W1w, W1b, e_out, NE, rtE32,
      src, dst, W2h, W3h, nullptr,nullptr,nullptr,nullptr,nullptr,nullptr,nullptr, eSum, eSumSq);

  finalizeE_k<<<1, 128, 0, stream>>>(eSum, eSumSq, (double)NE, mF, rF);

  // e_new = e@Wemb_e + relu(bn(pre_e)) in place over e_out
  gemm32_k<2><<<4096, blk, 0, stream>>>(e, Wemb_e, nullptr, e_out, NE, rtE32,
      nullptr,nullptr,nullptr,nullptr, mF, rF, e_gamma, e_beta, nullptr,nullptr,nullptr,nullptr,nullptr);

  // sigma = sigmoid(e_new)@W_eta; den[dst]+=sigma, num[dst]+=sigma*Vh[src]
  gemm32_k<3><<<4096, blk, 0, stream>>>(e_out, Wemb_eta, nullptr, nullptr, NE, rtE32,
      src, dst, nullptr,nullptr,nullptr,nullptr,nullptr,nullptr, den, num, Vh, nullptr,nullptr);

  // pre_h = Uh + num/(den+1e-5f) in place over d_out h-region
  combine_k<<<2048, blk, 0, stream>>>(h_new_out, num, den, (long)NN * DD / 4);

  stats64_k<<<512, blk, 0, stream>>>(h_new_out, NN, hSum, hSumSq);
  finalize64_k<<<1, 128, 0, stream>>>(hSum, hSumSq, (double)NN, h_gamma, h_beta, hScale, hShift);

  // h_new = h@Wemb_n + relu(bn(pre_h))  (MFMA; post-division path)
  hfinal_mfma_k<<<dim3(rtN64, 2), blk, 0, stream>>>(h, Wemb_n, h_new_out, NN, rtN64,
      h_new_out, hScale, hShift);
}

// Round 5
// 1704.879 us; speedup vs baseline: 1.3904x; 1.3904x over previous
//
#include <hip/hip_runtime.h>
#include <cstdint>
#include <cstddef>
#include <cmath>

#define DD 128

typedef short bf16x8 __attribute__((ext_vector_type(8)));
typedef float f32x4 __attribute__((ext_vector_type(4)));

static __device__ __forceinline__ short f2bf(float f){
  union { float f; uint32_t u; } v; v.f = f;
  uint32_t r = v.u + 0x7FFFu + ((v.u >> 16) & 1u);   // RNE
  return (short)(r >> 16);
}
static __device__ __forceinline__ float bf2f(short h){
  union { uint32_t u; float f; } v; v.u = ((uint32_t)(uint16_t)h) << 16;
  return v.f;
}

// ============================================================================
// f32 GEMM mimicking BLAS sgemm rounding: per output element a SINGLE
// sequential fmaf chain over k=0..127.
// EP 0: Y = acc + bias
// EP 1: Y = ((acc + bias) + T2[src]) + T3[dst]; fused f64 BN stats
// EP 2: Y = acc + relu(((Y - m)*r)*gamma + beta)     (e_new; Y holds pre_e)
// ============================================================================
template<int EP>
__global__ __launch_bounds__(256, 1) void gemm32_k(
    const float* __restrict__ X, const float* __restrict__ W,
    const float* __restrict__ bias, float* __restrict__ Y,
    int M, int rowTiles,
    const int* __restrict__ src, const int* __restrict__ dst,
    const float* __restrict__ T2, const float* __restrict__ T3,
    const float* __restrict__ mF, const float* __restrict__ rF,
    const float* __restrict__ gammaF, const float* __restrict__ betaF,
    double* __restrict__ eSum, double* __restrict__ eSumSq)
{
  __shared__ float sW[128 * 128];
  __shared__ float sA[128 * 32];
  __shared__ double redS[(EP == 1) ? 1024 : 1];
  __shared__ double redQ[(EP == 1) ? 1024 : 1];

  const int tid = threadIdx.x, tx = tid & 31, ty = tid >> 5, c0 = tx * 4;

  for (int t = tid; t < 128 * 128 / 4; t += 256)
    ((f32x4*)sW)[t] = ((const f32x4*)W)[t];

  float bias_c[4];
  #pragma unroll
  for (int j = 0; j < 4; ++j) bias_c[j] = bias ? bias[c0 + j] : 0.0f;

  double st_s[4] = {0,0,0,0}, st_q[4] = {0,0,0,0};
  __syncthreads();

  for (int rt = blockIdx.x; rt < rowTiles; rt += gridDim.x){
    const int rowBase = rt * 32;
    { // stage A (32 rows x 128 k), transposed to [k][row]
      int rr = tid & 31;
      int kk = (tid >> 5) * 16;
      int ar = rowBase + rr; if (ar >= M) ar = M - 1;
      const float* xp = X + (size_t)ar * DD + kk;
      #pragma unroll
      for (int q = 0; q < 4; ++q){
        f32x4 v = *(const f32x4*)(xp + q * 4);
        #pragma unroll
        for (int j = 0; j < 4; ++j) sA[(kk + q*4 + j) * 32 + rr] = v[j];
      }
    }
    __syncthreads();

    float acc[4][4] = {};
    for (int k = 0; k < 128; ++k){            // sequential k: BLAS-order chain
      f32x4 a = *(const f32x4*)&sA[k * 32 + ty * 4];
      f32x4 b = *(const f32x4*)&sW[k * 128 + c0];
      #pragma unroll
      for (int i = 0; i < 4; ++i)
        #pragma unroll
        for (int j = 0; j < 4; ++j)
          acc[i][j] = fmaf(a[i], b[j], acc[i][j]);
    }

    #pragma unroll
    for (int i = 0; i < 4; ++i){
      int r = rowBase + ty * 4 + i;
      if (r < M){
        size_t base = (size_t)r * DD + c0;
        if (EP == 0){
          #pragma unroll
          for (int j = 0; j < 4; ++j) Y[base + j] = acc[i][j] + bias_c[j];
        } else if (EP == 1){
          int s = src[r], d = dst[r];
          f32x4 t2 = *(const f32x4*)&T2[(size_t)s * DD + c0];
          f32x4 t3 = *(const f32x4*)&T3[(size_t)d * DD + c0];
          #pragma unroll
          for (int j = 0; j < 4; ++j){
            float o = ((acc[i][j] + bias_c[j]) + t2[j]) + t3[j];  // ref add order
            Y[base + j] = o;
            st_s[j] += (double)o;
            st_q[j] += (double)o * (double)o;
          }
        } else { // EP 2
          f32x4 pe = *(const f32x4*)&Y[base];      // pre_e (stored f32)
          #pragma unroll
          for (int j = 0; j < 4; ++j){
            float xm = pe[j] - mF[c0 + j];
            float t1 = xm * rF[c0 + j];
            float t2v = t1 * gammaF[c0 + j];
            float t3v = t2v + betaF[c0 + j];
            float t = fmaxf(t3v, 0.0f);
            Y[base + j] = acc[i][j] + t;           // e_new = e_emb + relu(bn)
          }
        }
      }
    }
    __syncthreads();
  }

  if (EP == 1){
    const int idx = tx * 8 + ty;
    #pragma unroll
    for (int j = 0; j < 4; ++j){ redS[idx*4+j] = st_s[j]; redQ[idx*4+j] = st_q[j]; }
    __syncthreads();
    if (ty == 0){
      #pragma unroll
      for (int j = 0; j < 4; ++j){
        double s = 0.0, q = 0.0;
        #pragma unroll
        for (int t = 0; t < 8; ++t){ s += redS[(tx*8+t)*4+j]; q += redQ[(tx*8+t)*4+j]; }
        atomicAdd(&eSum[c0+j], s);
        atomicAdd(&eSumSq[c0+j], q);
      }
    }
  }
}

// ---------------- CSR build: bucket edges by dst ----------------
__global__ void hist_k(const int* __restrict__ dst, int NE, int* __restrict__ counts){
  int i = blockIdx.x * blockDim.x + threadIdx.x;
  if (i < NE) atomicAdd(&counts[dst[i]], 1);
}

__global__ __launch_bounds__(1024, 1) void scan_k(const int* __restrict__ counts, int NN,
                                                  int* __restrict__ rowStart, int* __restrict__ cursor){
  __shared__ int part[1024];
  const int T = 1024, t = threadIdx.x;
  const int chunk = (NN + T - 1) / T;
  const int lo = t * chunk;
  const int hi = (lo + chunk < NN) ? lo + chunk : NN;
  int s = 0;
  for (int i = lo; i < hi; ++i) s += counts[i];
  part[t] = s;
  __syncthreads();
  for (int off = 1; off < T; off <<= 1){
    int v = (t >= off) ? part[t - off] : 0;
    __syncthreads();
    part[t] += v;
    __syncthreads();
  }
  int run = (t == 0) ? 0 : part[t - 1];
  for (int i = lo; i < hi; ++i){ rowStart[i] = run; cursor[i] = run; run += counts[i]; }
  if (t == T - 1) rowStart[NN] = run;
}

__global__ void place_k(const int* __restrict__ dst, int NE,
                        int* __restrict__ cursor, int* __restrict__ edgeIdx){
  int i = blockIdx.x * blockDim.x + threadIdx.x;
  if (i < NE){ int p = atomicAdd(&cursor[dst[i]], 1); edgeIdx[p] = i; }
}

// ============================================================================
// Node-centric aggregation, zero global atomics. One wave per node:
//   sigma_e = sigmoid(e_new[e]) @ Weta  (f32 sequential-k dot, Weta in LDS)
//   den += sigma_e ; num += sigma_e * Vh[src[e]]   (bucket order, registers)
//   pre_h = Uh + num/(den + 1e-5f)
// 4 edges in flight per wave for ILP. Lane owns cols {lane, lane+64}.
// ============================================================================
__global__ __launch_bounds__(256, 2) void agg_k(
    const float* __restrict__ e_new, const float* __restrict__ Weta,
    const float* __restrict__ Vh,
    const int* __restrict__ rowStart, const int* __restrict__ edgeIdx,
    const int* __restrict__ srcArr,
    const float* __restrict__ Uh, float* __restrict__ preH, int NN)
{
  __shared__ float sW[128 * 128];       // 64 KB
  __shared__ float rows[4][4][128];     // 8 KB  [wave][edge-slot][k]
  const int tid = threadIdx.x, lane = tid & 63, wv = tid >> 6;

  for (int t = tid; t < 128 * 128 / 4; t += 256)
    ((f32x4*)sW)[t] = ((const f32x4*)Weta)[t];
  __syncthreads();

  for (int node = blockIdx.x * 4 + wv; node < NN; node += gridDim.x * 4){
    const int beg = rowStart[node], end = rowStart[node + 1];
    float den0 = 0.f, den1 = 0.f, num0 = 0.f, num1 = 0.f;

    for (int eb = beg; eb < end; eb += 4){
      const int nE = end - eb;
      float vh0[4], vh1[4];
      #pragma unroll
      for (int q = 0; q < 4; ++q){
        if (q < nE){
          int eid = edgeIdx[eb + q];
          int s = srcArr[eid];
          float r0 = e_new[(size_t)eid * DD + lane];
          float r1 = e_new[(size_t)eid * DD + 64 + lane];
          rows[wv][q][lane]      = 1.0f / (1.0f + expf(-r0));
          rows[wv][q][64 + lane] = 1.0f / (1.0f + expf(-r1));
          vh0[q] = Vh[(size_t)s * DD + lane];
          vh1[q] = Vh[(size_t)s * DD + 64 + lane];
        } else {
          rows[wv][q][lane] = 0.f; rows[wv][q][64 + lane] = 0.f;
          vh0[q] = 0.f; vh1[q] = 0.f;
        }
      }
      // wave-coherent LDS: compiler inserts lgkmcnt wait before reads
      float sg0[4] = {0,0,0,0}, sg1[4] = {0,0,0,0};
      for (int k = 0; k < 128; ++k){
        float w0 = sW[k * DD + lane];
        float w1 = sW[k * DD + 64 + lane];
        #pragma unroll
        for (int q = 0; q < 4; ++q){
          float a = rows[wv][q][k];            // broadcast read
          sg0[q] = fmaf(a, w0, sg0[q]);
          sg1[q] = fmaf(a, w1, sg1[q]);
        }
      }
      #pragma unroll
      for (int q = 0; q < 4; ++q){
        den0 += sg0[q]; den1 += sg1[q];
        num0 = fmaf(sg0[q], vh0[q], num0);
        num1 = fmaf(sg1[q], vh1[q], num1);
      }
    }
    const size_t b = (size_t)node * DD;
    preH[b + lane]      = Uh[b + lane]      + num0 / (den0 + 1e-5f);
    preH[b + 64 + lane] = Uh[b + 64 + lane] + num1 / (den1 + 1e-5f);
  }
}

// e-BN params: f64 stats -> f32 mean and f32 rsqrt
__global__ void finalizeE_k(const double* __restrict__ sum, const double* __restrict__ sumsq,
                            double M, float* __restrict__ mF, float* __restrict__ rF)
{
  int c = threadIdx.x;
  double m = sum[c] / M;
  double v = sumsq[c] / M - m * m;
  float vf = (float)v;
  mF[c] = (float)m;
  rF[c] = 1.0f / sqrtf(vf + 1e-5f);
}

// column stats (f32 in, f64 accum)
__global__ void stats64_k(const float* __restrict__ X, int M,
                          double* __restrict__ sum, double* __restrict__ sumsq)
{
  const int col = threadIdx.x & 127;
  const int half = threadIdx.x >> 7;
  double s = 0.0, q = 0.0;
  for (int r = blockIdx.x * 2 + half; r < M; r += gridDim.x * 2){
    double v = (double)X[(size_t)r * DD + col];
    s += v; q += v * v;
  }
  __shared__ double sS[256], sQ[256];
  sS[threadIdx.x] = s; sQ[threadIdx.x] = q;
  __syncthreads();
  if (half == 0){
    atomicAdd(&sum[col],   sS[col] + sS[col + 128]);
    atomicAdd(&sumsq[col], sQ[col] + sQ[col + 128]);
  }
}

__global__ void finalize64_k(const double* __restrict__ sum, const double* __restrict__ sumsq,
                             double M, const float* __restrict__ gamma, const float* __restrict__ beta,
                             double* __restrict__ scale, double* __restrict__ shift)
{
  int c = threadIdx.x;
  double m = sum[c] / M;
  double var = sumsq[c] / M - m * m;
  double sc = (double)gamma[c] / sqrt(var + 1e-5);
  scale[c] = sc;
  shift[c] = (double)beta[c] - m * sc;
}

// ---------------- split-bf16 MFMA GEMM: h_new = h@Wemb_n + relu(bn(pre_h)) ----
__global__ __launch_bounds__(256, 2) void hfinal_mfma_k(
    const float* __restrict__ X, const float* __restrict__ W,
    float* __restrict__ Y, int M, int rowTiles,
    const float* __restrict__ preH,
    const double* __restrict__ hSc, const double* __restrict__ hSh)
{
  const int tid = threadIdx.x;
  const int lane = tid & 63;
  const int wv = tid >> 6;
  const int l15 = lane & 15;
  const int lg = lane >> 4;
  const int colBase = blockIdx.y * 64;

  __shared__ short sW[2][64][136];
  for (int t = tid; t < 64 * 128; t += 256){
    int k = t >> 6, nl = t & 63;
    float w = W[k * DD + colBase + nl];
    short hi = f2bf(w);
    sW[0][nl][k] = hi;
    sW[1][nl][k] = f2bf(w - bf2f(hi));
  }
  __syncthreads();

  bf16x8 Bhi[4][4], Blo[4][4];
  #pragma unroll
  for (int ct = 0; ct < 4; ++ct)
    #pragma unroll
    for (int ks = 0; ks < 4; ++ks){
      Bhi[ct][ks] = *(const bf16x8*)&sW[0][ct*16 + l15][ks*32 + lg*8];
      Blo[ct][ks] = *(const bf16x8*)&sW[1][ct*16 + l15][ks*32 + lg*8];
    }

  for (int rt = blockIdx.x; rt < rowTiles; rt += gridDim.x){
    int arow = rt * 64 + wv * 16 + l15;
    if (arow >= M) arow = M - 1;
    const f32x4* xr = (const f32x4*)(X + (size_t)arow * DD);

    bf16x8 Ahi[4], Alo[4];
    #pragma unroll
    for (int ks = 0; ks < 4; ++ks){
      f32x4 a0 = xr[ks*8 + lg*2];
      f32x4 a1 = xr[ks*8 + lg*2 + 1];
      float av[8];
      #pragma unroll
      for (int j = 0; j < 4; ++j){ av[j] = a0[j]; av[4+j] = a1[j]; }
      #pragma unroll
      for (int j = 0; j < 8; ++j){
        short hi = f2bf(av[j]);
        Ahi[ks][j] = hi;
        Alo[ks][j] = f2bf(av[j] - bf2f(hi));
      }
    }

    f32x4 acc[4];
    #pragma unroll
    for (int ct = 0; ct < 4; ++ct) acc[ct] = (f32x4){0.f, 0.f, 0.f, 0.f};
    #pragma unroll
    for (int ct = 0; ct < 4; ++ct)
      #pragma unroll
      for (int ks = 0; ks < 4; ++ks){
        acc[ct] = __builtin_amdgcn_mfma_f32_16x16x32_bf16(Ahi[ks], Bhi[ct][ks], acc[ct], 0, 0, 0);
        acc[ct] = __builtin_amdgcn_mfma_f32_16x16x32_bf16(Ahi[ks], Blo[ct][ks], acc[ct], 0, 0, 0);
        acc[ct] = __builtin_amdgcn_mfma_f32_16x16x32_bf16(Alo[ks], Bhi[ct][ks], acc[ct], 0, 0, 0);
      }

    const int r0 = rt * 64 + wv * 16 + lg * 4;
    #pragma unroll
    for (int reg = 0; reg < 4; ++reg){
      int r = r0 + reg;
      if (r < M){
        #pragma unroll
        for (int ct = 0; ct < 4; ++ct){
          int c = colBase + ct*16 + l15;
          double t = (double)preH[(size_t)r * DD + c] * hSc[c] + hSh[c];
          float tv = t > 0.0 ? (float)t : 0.0f;
          Y[(size_t)r * DD + c] = acc[ct][reg] + tv;
        }
      }
    }
  }
}

extern "C" void kernel_launch(void* const* d_in, const int* in_sizes, int n_in,
                              void* d_out, int out_size, void* d_ws, size_t ws_size,
                              hipStream_t stream)
{
  const float* h  = (const float*)d_in[0];
  const float* e  = (const float*)d_in[1];
  const int* src  = (const int*)d_in[2];
  const int* dst  = (const int*)d_in[3];
  const float* Wemb_n   = (const float*)d_in[4];
  const float* Wemb_e   = (const float*)d_in[5];
  const float* Wemb_eta = (const float*)d_in[6];
  const float* Uw  = (const float*)d_in[7];  const float* Ub  = (const float*)d_in[8];
  const float* Vw  = (const float*)d_in[9];  const float* Vb  = (const float*)d_in[10];
  const float* W1w = (const float*)d_in[11]; const float* W1b = (const float*)d_in[12];
  const float* W2w = (const float*)d_in[13]; const float* W2b = (const float*)d_in[14];
  const float* W3w = (const float*)d_in[15]; const float* W3b = (const float*)d_in[16];
  const float* h_gamma = (const float*)d_in[17]; const float* h_beta = (const float*)d_in[18];
  const float* e_gamma = (const float*)d_in[19]; const float* e_beta = (const float*)d_in[20];

  const int NN = in_sizes[0] / DD;   // 50000
  const int NE = in_sizes[2];        // 400000

  // workspace: W2h | W3h | Vh (f32 NN*DD) | stats f64 | mF,rF | CSR ints
  char* wsp = (char*)d_ws;
  float* W2h = (float*)wsp;  wsp += (size_t)NN * DD * sizeof(float);
  float* W3h = (float*)wsp;  wsp += (size_t)NN * DD * sizeof(float);
  float* Vh  = (float*)wsp;  wsp += (size_t)NN * DD * sizeof(float);
  double* stats = (double*)wsp; wsp += 6 * DD * sizeof(double);
  double* eSum = stats;        double* eSumSq = stats + DD;
  double* hSum = stats + 2*DD; double* hSumSq = stats + 3*DD;
  double* hScale = stats + 4*DD; double* hShift = stats + 5*DD;
  float* mF = (float*)wsp;   wsp += DD * sizeof(float);
  float* rF = (float*)wsp;   wsp += DD * sizeof(float);
  int* counts   = (int*)wsp; wsp += (size_t)NN * sizeof(int);
  int* rowStart = (int*)wsp; wsp += ((size_t)NN + 1) * sizeof(int);
  int* cursor   = (int*)wsp; wsp += (size_t)NN * sizeof(int);
  int* edgeIdx  = (int*)wsp; wsp += (size_t)NE * sizeof(int);

  float* h_new_out = (float*)d_out;                    // Uh -> pre_h -> h_new
  float* e_out     = (float*)d_out + (size_t)NN * DD;  // pre_e -> e_new

  const int rtN32 = (NN + 31) / 32;   // 1563
  const int rtE32 = (NE + 31) / 32;   // 12500
  const int rtN64 = (NN + 63) / 64;
  dim3 blk(256);

  hipMemsetAsync(stats, 0, (size_t)4 * DD * sizeof(double), stream);
  hipMemsetAsync(counts, 0, (size_t)NN * sizeof(int), stream);

  // CSR build (independent of GEMMs)
  hist_k<<<(NE + 255) / 256, blk, 0, stream>>>(dst, NE, counts);
  scan_k<<<1, 1024, 0, stream>>>(counts, NN, rowStart, cursor);
  place_k<<<(NE + 255) / 256, blk, 0, stream>>>(dst, NE, cursor, edgeIdx);

  // node GEMMs, f32 BLAS-order
  gemm32_k<0><<<rtN32, blk, 0, stream>>>(h, Uw, Ub, h_new_out, NN, rtN32,
      nullptr,nullptr,nullptr,nullptr,nullptr,nullptr,nullptr,nullptr,nullptr,nullptr);
  gemm32_k<0><<<rtN32, blk, 0, stream>>>(h, Vw, Vb, Vh, NN, rtN32,
      nullptr,nullptr,nullptr,nullptr,nullptr,nullptr,nullptr,nullptr,nullptr,nullptr);
  gemm32_k<0><<<rtN32, blk, 0, stream>>>(h, W2w, W2b, W2h, NN, rtN32,
      nullptr,nullptr,nullptr,nullptr,nullptr,nullptr,nullptr,nullptr,nullptr,nullptr);
  gemm32_k<0><<<rtN32, blk, 0, stream>>>(h, W3w, W3b, W3h, NN, rtN32,
      nullptr,nullptr,nullptr,nullptr,nullptr,nullptr,nullptr,nullptr,nullptr,nullptr);

  // pre_e = ((e@W1 + W1b) + W2h[src]) + W3h[dst] -> e_out; fused f64 stats
  gemm32_k<1><<<4096, blk, 0, stream>>>(e, W1w, W1b, e_out, NE, rtE32,
      src, dst, W2h, W3h, nullptr,nullptr,nullptr,nullptr, eSum, eSumSq);

  finalizeE_k<<<1, 128, 0, stream>>>(eSum, eSumSq, (double)NE, mF, rF);

  // e_new = e@Wemb_e + relu(bn(pre_e)) in place over e_out
  gemm32_k<2><<<4096, blk, 0, stream>>>(e, Wemb_e, nullptr, e_out, NE, rtE32,
      nullptr,nullptr,nullptr,nullptr, mF, rF, e_gamma, e_beta, nullptr,nullptr);

  // node-centric aggregation: pre_h = Uh + num/(den+1e-5)  (in place over d_out)
  agg_k<<<(NN + 3) / 4, blk, 0, stream>>>(e_out, Wemb_eta, Vh,
      rowStart, edgeIdx, src, h_new_out, h_new_out, NN);

  stats64_k<<<512, blk, 0, stream>>>(h_new_out, NN, hSum, hSumSq);
  finalize64_k<<<1, 128, 0, stream>>>(hSum, hSumSq, (double)NN, h_gamma, h_beta, hScale, hShift);

  // h_new = h@Wemb_n + relu(bn(pre_h))  (MFMA; post-division path)
  hfinal_mfma_k<<<dim3(rtN64, 2), blk, 0, stream>>>(h, Wemb_n, h_new_out, NN, rtN64,
      h_new_out, hScale, hShift);
}

// Round 6
// 1222.639 us; speedup vs baseline: 1.9388x; 1.3944x over previous
//
#include <hip/hip_runtime.h>
#include <cstdint>
#include <cstddef>
#include <cmath>

#define DD 128

typedef short bf16x8 __attribute__((ext_vector_type(8)));
typedef float f32x4 __attribute__((ext_vector_type(4)));

static __device__ __forceinline__ short f2bf(float f){
  union { float f; uint32_t u; } v; v.f = f;
  uint32_t r = v.u + 0x7FFFu + ((v.u >> 16) & 1u);   // RNE
  return (short)(r >> 16);
}
static __device__ __forceinline__ float bf2f(short h){
  union { uint32_t u; float f; } v; v.u = ((uint32_t)(uint16_t)h) << 16;
  return v.f;
}
static __device__ __forceinline__ double shfl_xor_f64(double v, int m){
  long long l = __double_as_longlong(v);
  int lo = (int)(l & 0xffffffffLL);
  int hi = (int)((unsigned long long)l >> 32);
  lo = __shfl_xor(lo, m, 64);
  hi = __shfl_xor(hi, m, 64);
  return __longlong_as_double(((long long)hi << 32) | (unsigned long long)(unsigned int)lo);
}

// ============================================================================
// Fast f32 GEMM with BLAS-identical rounding: each output element is ONE
// sequential fmaf chain over k=0..127. 128x128 block tile, 16x4 per thread.
// k processed in two 64-halves to keep LDS at 67KB (2 blocks/CU).
// EP 0: Y = acc + bias
// EP 1: Y = ((acc + bias) + T2[src]) + T3[dst]; fused f64 BN stats
// EP 2: Y = acc + relu(((Y - m)*r)*gamma + beta)     (e_new; Y holds pre_e)
// EP 3: A-staged as sigmoid(X); Y = acc              (sigma)
// ============================================================================
template<int EP>
__global__ __launch_bounds__(256, 2) void fgemm_k(
    const float* __restrict__ X, const float* __restrict__ W,
    const float* __restrict__ bias, float* __restrict__ Y,
    int M, int nTiles,
    const int* __restrict__ src, const int* __restrict__ dst,
    const float* __restrict__ T2, const float* __restrict__ T3,
    const float* __restrict__ mF, const float* __restrict__ rF,
    const float* __restrict__ gammaF, const float* __restrict__ betaF,
    double* __restrict__ eSum, double* __restrict__ eSumSq)
{
  __shared__ float sA[128][68];            // [row][k-half] pad->row stride 272B (16B aligned)
  __shared__ float sW[64][128];            // [k-half][col]
  __shared__ double redS[(EP == 1) ? 4 : 1][32][4];
  __shared__ double redQ[(EP == 1) ? 4 : 1][32][4];

  const int tid = threadIdx.x;
  const int tx = tid & 31;          // col group: c0 = tx*4
  const int ty = tid >> 5;          // row group: r0 = ty*16
  const int c0 = tx * 4;
  const int r0 = ty * 16;
  const int lane = tid & 63, wv = tid >> 6;

  float bias_c[4];
  #pragma unroll
  for (int j = 0; j < 4; ++j) bias_c[j] = bias ? bias[c0 + j] : 0.0f;

  double st_s[4] = {0,0,0,0}, st_q[4] = {0,0,0,0};

  for (int tile = blockIdx.x; tile < nTiles; tile += gridDim.x){
    const int rowBase = tile * 128;
    float acc[16][4];
    #pragma unroll
    for (int r = 0; r < 16; ++r)
      #pragma unroll
      for (int j = 0; j < 4; ++j) acc[r][j] = 0.0f;

    #pragma unroll
    for (int h = 0; h < 2; ++h){
      // stage sW half: 64 x 128
      {
        int kk = ty * 8;
        #pragma unroll
        for (int q = 0; q < 8; ++q)
          *(f32x4*)&sW[kk + q][c0] = *(const f32x4*)&W[(size_t)(h*64 + kk + q) * DD + c0];
      }
      // stage sA half: 128 rows x 64 k (row-major, coalesced)
      {
        int r = tid >> 1;
        int koff = (tid & 1) * 32;
        int ar = rowBase + r; if (ar >= M) ar = M - 1;
        const float* xp = X + (size_t)ar * DD + h*64 + koff;
        #pragma unroll
        for (int q = 0; q < 8; ++q){
          f32x4 v = *(const f32x4*)(xp + q * 4);
          if (EP == 3){
            #pragma unroll
            for (int j = 0; j < 4; ++j) v[j] = 1.0f / (1.0f + expf(-v[j]));
          }
          *(f32x4*)&sA[r][koff + q * 4] = v;
        }
      }
      __syncthreads();

      #pragma unroll 2
      for (int q = 0; q < 16; ++q){          // 16 quads of 4 k
        f32x4 b0 = *(const f32x4*)&sW[4*q + 0][c0];
        f32x4 b1 = *(const f32x4*)&sW[4*q + 1][c0];
        f32x4 b2 = *(const f32x4*)&sW[4*q + 2][c0];
        f32x4 b3 = *(const f32x4*)&sW[4*q + 3][c0];
        #pragma unroll
        for (int r = 0; r < 16; ++r){
          f32x4 a = *(const f32x4*)&sA[r0 + r][4*q];
          #pragma unroll
          for (int j = 0; j < 4; ++j){
            // sequential k order preserved: k, k+1, k+2, k+3
            acc[r][j] = fmaf(a[0], b0[j], acc[r][j]);
            acc[r][j] = fmaf(a[1], b1[j], acc[r][j]);
            acc[r][j] = fmaf(a[2], b2[j], acc[r][j]);
            acc[r][j] = fmaf(a[3], b3[j], acc[r][j]);
          }
        }
      }
      __syncthreads();
    }

    // epilogue
    #pragma unroll
    for (int r = 0; r < 16; ++r){
      int row = rowBase + r0 + r;
      if (row < M){
        size_t base = (size_t)row * DD + c0;
        if (EP == 0){
          f32x4 o;
          #pragma unroll
          for (int j = 0; j < 4; ++j) o[j] = acc[r][j] + bias_c[j];
          *(f32x4*)&Y[base] = o;
        } else if (EP == 1){
          int s = src[row], d = dst[row];
          f32x4 t2 = *(const f32x4*)&T2[(size_t)s * DD + c0];
          f32x4 t3 = *(const f32x4*)&T3[(size_t)d * DD + c0];
          f32x4 o;
          #pragma unroll
          for (int j = 0; j < 4; ++j){
            o[j] = ((acc[r][j] + bias_c[j]) + t2[j]) + t3[j];   // ref add order
            st_s[j] += (double)o[j];
            st_q[j] += (double)o[j] * (double)o[j];
          }
          *(f32x4*)&Y[base] = o;
        } else if (EP == 2){
          f32x4 pe = *(const f32x4*)&Y[base];
          f32x4 o;
          #pragma unroll
          for (int j = 0; j < 4; ++j){
            float xm  = pe[j] - mF[c0 + j];
            float t1  = xm * rF[c0 + j];
            float t2v = t1 * gammaF[c0 + j];
            float t3v = t2v + betaF[c0 + j];
            float t = fmaxf(t3v, 0.0f);
            o[j] = acc[r][j] + t;            // e_new = e_emb + relu(bn)
          }
          *(f32x4*)&Y[base] = o;
        } else { // EP 3: sigma
          f32x4 o;
          #pragma unroll
          for (int j = 0; j < 4; ++j) o[j] = acc[r][j];
          *(f32x4*)&Y[base] = o;
        }
      }
    }
  }

  if (EP == 1){
    // reduce ty-pairs within wave (lane ^ 32 shares tx)
    #pragma unroll
    for (int j = 0; j < 4; ++j){
      st_s[j] += shfl_xor_f64(st_s[j], 32);
      st_q[j] += shfl_xor_f64(st_q[j], 32);
    }
    if (lane < 32){
      #pragma unroll
      for (int j = 0; j < 4; ++j){ redS[wv][lane][j] = st_s[j]; redQ[wv][lane][j] = st_q[j]; }
    }
    __syncthreads();
    if (tid < 128){
      int txx = tid >> 2, j = tid & 3;
      double s = 0.0, q = 0.0;
      #pragma unroll
      for (int w = 0; w < 4; ++w){ s += redS[w][txx][j]; q += redQ[w][txx][j]; }
      atomicAdd(&eSum[txx*4 + j], s);
      atomicAdd(&eSumSq[txx*4 + j], q);
    }
  }
}

// ---------------- CSR build: bucket edges by dst ----------------
__global__ void hist_k(const int* __restrict__ dst, int NE, int* __restrict__ counts){
  int i = blockIdx.x * blockDim.x + threadIdx.x;
  if (i < NE) atomicAdd(&counts[dst[i]], 1);
}

__global__ __launch_bounds__(1024, 1) void scan_k(const int* __restrict__ counts, int NN,
                                                  int* __restrict__ rowStart, int* __restrict__ cursor){
  __shared__ int part[1024];
  const int T = 1024, t = threadIdx.x;
  const int chunk = (NN + T - 1) / T;
  const int lo = t * chunk;
  const int hi = (lo + chunk < NN) ? lo + chunk : NN;
  int s = 0;
  for (int i = lo; i < hi; ++i) s += counts[i];
  part[t] = s;
  __syncthreads();
  for (int off = 1; off < T; off <<= 1){
    int v = (t >= off) ? part[t - off] : 0;
    __syncthreads();
    part[t] += v;
    __syncthreads();
  }
  int run = (t == 0) ? 0 : part[t - 1];
  for (int i = lo; i < hi; ++i){ rowStart[i] = run; cursor[i] = run; run += counts[i]; }
  if (t == T - 1) rowStart[NN] = run;
}

__global__ void place_k(const int* __restrict__ dst, int NE,
                        int* __restrict__ cursor, int* __restrict__ edgeIdx){
  int i = blockIdx.x * blockDim.x + threadIdx.x;
  if (i < NE){ int p = atomicAdd(&cursor[dst[i]], 1); edgeIdx[p] = i; }
}

// ---------------- gather-reduce: den/num from dense sigma, bucket order ------
__global__ __launch_bounds__(256, 4) void gather_k(
    const float* __restrict__ sigma, const float* __restrict__ Vh,
    const int* __restrict__ rowStart, const int* __restrict__ edgeIdx,
    const int* __restrict__ srcArr,
    const float* __restrict__ Uh, float* __restrict__ preH, int NN)
{
  const int lane = threadIdx.x & 63, wv = threadIdx.x >> 6;
  for (int node = blockIdx.x * 4 + wv; node < NN; node += gridDim.x * 4){
    const int beg = rowStart[node], end = rowStart[node + 1];
    float den0 = 0.f, den1 = 0.f, num0 = 0.f, num1 = 0.f;
    for (int eb = beg; eb < end; eb += 4){
      const int nE = end - eb;
      float sg0[4], sg1[4], vh0[4], vh1[4];
      #pragma unroll
      for (int q = 0; q < 4; ++q){
        if (q < nE){
          int eid = edgeIdx[eb + q];
          int s = srcArr[eid];
          sg0[q] = sigma[(size_t)eid * DD + lane];
          sg1[q] = sigma[(size_t)eid * DD + 64 + lane];
          vh0[q] = Vh[(size_t)s * DD + lane];
          vh1[q] = Vh[(size_t)s * DD + 64 + lane];
        } else { sg0[q] = 0.f; sg1[q] = 0.f; vh0[q] = 0.f; vh1[q] = 0.f; }
      }
      #pragma unroll
      for (int q = 0; q < 4; ++q){
        den0 += sg0[q]; den1 += sg1[q];
        num0 = fmaf(sg0[q], vh0[q], num0);
        num1 = fmaf(sg1[q], vh1[q], num1);
      }
    }
    const size_t b = (size_t)node * DD;
    preH[b + lane]      = Uh[b + lane]      + num0 / (den0 + 1e-5f);
    preH[b + 64 + lane] = Uh[b + 64 + lane] + num1 / (den1 + 1e-5f);
  }
}

// e-BN params: f64 stats -> f32 mean and f32 rsqrt
__global__ void finalizeE_k(const double* __restrict__ sum, const double* __restrict__ sumsq,
                            double M, float* __restrict__ mF, float* __restrict__ rF)
{
  int c = threadIdx.x;
  double m = sum[c] / M;
  double v = sumsq[c] / M - m * m;
  float vf = (float)v;
  mF[c] = (float)m;
  rF[c] = 1.0f / sqrtf(vf + 1e-5f);
}

// column stats (f32 in, f64 accum)
__global__ void stats64_k(const float* __restrict__ X, int M,
                          double* __restrict__ sum, double* __restrict__ sumsq)
{
  const int col = threadIdx.x & 127;
  const int half = threadIdx.x >> 7;
  double s = 0.0, q = 0.0;
  for (int r = blockIdx.x * 2 + half; r < M; r += gridDim.x * 2){
    double v = (double)X[(size_t)r * DD + col];
    s += v; q += v * v;
  }
  __shared__ double sS[256], sQ[256];
  sS[threadIdx.x] = s; sQ[threadIdx.x] = q;
  __syncthreads();
  if (half == 0){
    atomicAdd(&sum[col],   sS[col] + sS[col + 128]);
    atomicAdd(&sumsq[col], sQ[col] + sQ[col + 128]);
  }
}

__global__ void finalize64_k(const double* __restrict__ sum, const double* __restrict__ sumsq,
                             double M, const float* __restrict__ gamma, const float* __restrict__ beta,
                             double* __restrict__ scale, double* __restrict__ shift)
{
  int c = threadIdx.x;
  double m = sum[c] / M;
  double var = sumsq[c] / M - m * m;
  double sc = (double)gamma[c] / sqrt(var + 1e-5);
  scale[c] = sc;
  shift[c] = (double)beta[c] - m * sc;
}

// ---------------- split-bf16 MFMA GEMM: h_new = h@Wemb_n + relu(bn(pre_h)) ----
__global__ __launch_bounds__(256, 2) void hfinal_mfma_k(
    const float* __restrict__ X, const float* __restrict__ W,
    float* __restrict__ Y, int M, int rowTiles,
    const float* __restrict__ preH,
    const double* __restrict__ hSc, const double* __restrict__ hSh)
{
  const int tid = threadIdx.x;
  const int lane = tid & 63;
  const int wv = tid >> 6;
  const int l15 = lane & 15;
  const int lg = lane >> 4;
  const int colBase = blockIdx.y * 64;

  __shared__ short sW[2][64][136];
  for (int t = tid; t < 64 * 128; t += 256){
    int k = t >> 6, nl = t & 63;
    float w = W[k * DD + colBase + nl];
    short hi = f2bf(w);
    sW[0][nl][k] = hi;
    sW[1][nl][k] = f2bf(w - bf2f(hi));
  }
  __syncthreads();

  bf16x8 Bhi[4][4], Blo[4][4];
  #pragma unroll
  for (int ct = 0; ct < 4; ++ct)
    #pragma unroll
    for (int ks = 0; ks < 4; ++ks){
      Bhi[ct][ks] = *(const bf16x8*)&sW[0][ct*16 + l15][ks*32 + lg*8];
      Blo[ct][ks] = *(const bf16x8*)&sW[1][ct*16 + l15][ks*32 + lg*8];
    }

  for (int rt = blockIdx.x; rt < rowTiles; rt += gridDim.x){
    int arow = rt * 64 + wv * 16 + l15;
    if (arow >= M) arow = M - 1;
    const f32x4* xr = (const f32x4*)(X + (size_t)arow * DD);

    bf16x8 Ahi[4], Alo[4];
    #pragma unroll
    for (int ks = 0; ks < 4; ++ks){
      f32x4 a0 = xr[ks*8 + lg*2];
      f32x4 a1 = xr[ks*8 + lg*2 + 1];
      float av[8];
      #pragma unroll
      for (int j = 0; j < 4; ++j){ av[j] = a0[j]; av[4+j] = a1[j]; }
      #pragma unroll
      for (int j = 0; j < 8; ++j){
        short hi = f2bf(av[j]);
        Ahi[ks][j] = hi;
        Alo[ks][j] = f2bf(av[j] - bf2f(hi));
      }
    }

    f32x4 acc[4];
    #pragma unroll
    for (int ct = 0; ct < 4; ++ct) acc[ct] = (f32x4){0.f, 0.f, 0.f, 0.f};
    #pragma unroll
    for (int ct = 0; ct < 4; ++ct)
      #pragma unroll
      for (int ks = 0; ks < 4; ++ks){
        acc[ct] = __builtin_amdgcn_mfma_f32_16x16x32_bf16(Ahi[ks], Bhi[ct][ks], acc[ct], 0, 0, 0);
        acc[ct] = __builtin_amdgcn_mfma_f32_16x16x32_bf16(Ahi[ks], Blo[ct][ks], acc[ct], 0, 0, 0);
        acc[ct] = __builtin_amdgcn_mfma_f32_16x16x32_bf16(Alo[ks], Bhi[ct][ks], acc[ct], 0, 0, 0);
      }

    const int r0 = rt * 64 + wv * 16 + lg * 4;
    #pragma unroll
    for (int reg = 0; reg < 4; ++reg){
      int r = r0 + reg;
      if (r < M){
        #pragma unroll
        for (int ct = 0; ct < 4; ++ct){
          int c = colBase + ct*16 + l15;
          double t = (double)preH[(size_t)r * DD + c] * hSc[c] + hSh[c];
          float tv = t > 0.0 ? (float)t : 0.0f;
          Y[(size_t)r * DD + c] = acc[ct][reg] + tv;
        }
      }
    }
  }
}

extern "C" void kernel_launch(void* const* d_in, const int* in_sizes, int n_in,
                              void* d_out, int out_size, void* d_ws, size_t ws_size,
                              hipStream_t stream)
{
  const float* h  = (const float*)d_in[0];
  const float* e  = (const float*)d_in[1];
  const int* src  = (const int*)d_in[2];
  const int* dst  = (const int*)d_in[3];
  const float* Wemb_n   = (const float*)d_in[4];
  const float* Wemb_e   = (const float*)d_in[5];
  const float* Wemb_eta = (const float*)d_in[6];
  const float* Uw  = (const float*)d_in[7];  const float* Ub  = (const float*)d_in[8];
  const float* Vw  = (const float*)d_in[9];  const float* Vb  = (const float*)d_in[10];
  const float* W1w = (const float*)d_in[11]; const float* W1b = (const float*)d_in[12];
  const float* W2w = (const float*)d_in[13]; const float* W2b = (const float*)d_in[14];
  const float* W3w = (const float*)d_in[15]; const float* W3b = (const float*)d_in[16];
  const float* h_gamma = (const float*)d_in[17]; const float* h_beta = (const float*)d_in[18];
  const float* e_gamma = (const float*)d_in[19]; const float* e_beta = (const float*)d_in[20];

  const int NN = in_sizes[0] / DD;   // 50000
  const int NE = in_sizes[2];        // 400000

  // workspace: W2h | W3h | Vh | sigma | stats | mF,rF | CSR
  char* wsp = (char*)d_ws;
  float* W2h   = (float*)wsp;  wsp += (size_t)NN * DD * sizeof(float);
  float* W3h   = (float*)wsp;  wsp += (size_t)NN * DD * sizeof(float);
  float* Vh    = (float*)wsp;  wsp += (size_t)NN * DD * sizeof(float);
  float* sigma = (float*)wsp;  wsp += (size_t)NE * DD * sizeof(float);
  double* stats = (double*)wsp; wsp += 6 * DD * sizeof(double);
  double* eSum = stats;        double* eSumSq = stats + DD;
  double* hSum = stats + 2*DD; double* hSumSq = stats + 3*DD;
  double* hScale = stats + 4*DD; double* hShift = stats + 5*DD;
  float* mF = (float*)wsp;   wsp += DD * sizeof(float);
  float* rF = (float*)wsp;   wsp += DD * sizeof(float);
  int* counts   = (int*)wsp; wsp += (size_t)NN * sizeof(int);
  int* rowStart = (int*)wsp; wsp += ((size_t)NN + 1) * sizeof(int);
  int* cursor   = (int*)wsp; wsp += (size_t)NN * sizeof(int);
  int* edgeIdx  = (int*)wsp; wsp += (size_t)NE * sizeof(int);

  float* h_new_out = (float*)d_out;                    // Uh -> pre_h -> h_new
  float* e_out     = (float*)d_out + (size_t)NN * DD;  // pre_e -> e_new

  const int tN = (NN + 127) / 128;    // 391
  const int tE = (NE + 127) / 128;    // 3125
  const int rtN64 = (NN + 63) / 64;   // 782 (mfma)
  dim3 blk(256);

  hipMemsetAsync(stats, 0, (size_t)4 * DD * sizeof(double), stream);
  hipMemsetAsync(counts, 0, (size_t)NN * sizeof(int), stream);

  // CSR build
  hist_k<<<(NE + 255) / 256, blk, 0, stream>>>(dst, NE, counts);
  scan_k<<<1, 1024, 0, stream>>>(counts, NN, rowStart, cursor);
  place_k<<<(NE + 255) / 256, blk, 0, stream>>>(dst, NE, cursor, edgeIdx);

  // node GEMMs (f32 BLAS-order, fast tile)
  fgemm_k<0><<<tN, blk, 0, stream>>>(h, Uw, Ub, h_new_out, NN, tN,
      nullptr,nullptr,nullptr,nullptr,nullptr,nullptr,nullptr,nullptr,nullptr,nullptr);
  fgemm_k<0><<<tN, blk, 0, stream>>>(h, Vw, Vb, Vh, NN, tN,
      nullptr,nullptr,nullptr,nullptr,nullptr,nullptr,nullptr,nullptr,nullptr,nullptr);
  fgemm_k<0><<<tN, blk, 0, stream>>>(h, W2w, W2b, W2h, NN, tN,
      nullptr,nullptr,nullptr,nullptr,nullptr,nullptr,nullptr,nullptr,nullptr,nullptr);
  fgemm_k<0><<<tN, blk, 0, stream>>>(h, W3w, W3b, W3h, NN, tN,
      nullptr,nullptr,nullptr,nullptr,nullptr,nullptr,nullptr,nullptr,nullptr,nullptr);

  // pre_e = ((e@W1 + W1b) + W2h[src]) + W3h[dst] -> e_out; fused f64 stats
  fgemm_k<1><<<1024, blk, 0, stream>>>(e, W1w, W1b, e_out, NE, tE,
      src, dst, W2h, W3h, nullptr,nullptr,nullptr,nullptr, eSum, eSumSq);

  finalizeE_k<<<1, 128, 0, stream>>>(eSum, eSumSq, (double)NE, mF, rF);

  // e_new = e@Wemb_e + relu(bn(pre_e)) in place over e_out
  fgemm_k<2><<<tE, blk, 0, stream>>>(e, Wemb_e, nullptr, e_out, NE, tE,
      nullptr,nullptr,nullptr,nullptr, mF, rF, e_gamma, e_beta, nullptr,nullptr);

  // sigma = sigmoid(e_new) @ W_eta  (dense, into ws)
  fgemm_k<3><<<tE, blk, 0, stream>>>(e_out, Wemb_eta, nullptr, sigma, NE, tE,
      nullptr,nullptr,nullptr,nullptr,nullptr,nullptr,nullptr,nullptr,nullptr,nullptr);

  // bucket-order gather-reduce: pre_h = Uh + num/(den+1e-5)  (in place over d_out)
  gather_k<<<(NN + 3) / 4, blk, 0, stream>>>(sigma, Vh, rowStart, edgeIdx, src,
      h_new_out, h_new_out, NN);

  stats64_k<<<512, blk, 0, stream>>>(h_new_out, NN, hSum, hSumSq);
  finalize64_k<<<1, 128, 0, stream>>>(hSum, hSumSq, (double)NN, h_gamma, h_beta, hScale, hShift);

  // h_new = h@Wemb_n + relu(bn(pre_h))  (MFMA; post-division path)
  hfinal_mfma_k<<<dim3(rtN64, 2), blk, 0, stream>>>(h, Wemb_n, h_new_out, NN, rtN64,
      h_new_out, hScale, hShift);
}